// Round 10
// baseline (58.774 us; speedup 1.0000x reference)
//
#include <hip/hip_runtime.h>
#include <hip/hip_bf16.h>

// BlockLinear: out[h*64+i][b] = sum_j W[h][i][j] * inp[h*64+j][b]
// Round 10: TLP-max design. r7-r9 (pipeline/addressing variants) all flat at
// 54-55 us with occupancy stuck <=34% -> per-wave MLP is unfixable at source
// level; switch to many small cheap waves (copy-kernel style).
//  - Pre-kernel packs W into a bf16 FRAGMENT TABLE in d_ws (128 KB, L2-hot):
//    main kernel loads W frags as 8 coalesced uint4, no conversion.
//  - Wave = 16 cols x 64 rows: 24 loads, 8 MFMA, 4 float4 stores.
//  - 8192 blocks; VGPR ~90 -> ~24 waves/CU resident.
// Fragment layout (HW-validated r6-r9): lane l holds k = ks*32 + 8*(l>>4)+r;
// C/D: batch col m = 4*(l>>4)+reg, output row n = l&15.

constexpr int H = 16;
constexpr int D = 64;
constexpr int B = 32768;

using bf16x8 = __attribute__((ext_vector_type(8))) short;
using f32x4  = __attribute__((ext_vector_type(4))) float;

__device__ inline unsigned pk2(float a, float b) {
    __hip_bfloat162 h2 = __float22bfloat162_rn(make_float2(a, b));
    union { __hip_bfloat162 h; unsigned u; } c;
    c.h = h2;
    return c.u;   // low 16 = a, high 16 = b
}

// Pre-kernel: Wt[(h*8 + ni*2 + ks)*64 + l] = bf16x8 fragment chunk =
// W[h][16*ni + (l&15)][ks*32 + (l>>4)*8 + 0..7], packed as 4 u32.
__global__ void build_wt(const float* __restrict__ W, uint4* __restrict__ Wt)
{
    const int h = blockIdx.x;
    const int t = threadIdx.x;
    #pragma unroll
    for (int s = 0; s < 2; ++s) {
        const int c  = t + s * 256;          // chunk 0..511
        const int g  = c >> 6;               // frag group 0..7 (ni*2+ks)
        const int l  = c & 63;               // lane within frag
        const int ni = g >> 1;
        const int ks = g & 1;
        const int row = 16 * ni + (l & 15);
        const int col = ks * 32 + (l >> 4) * 8;
        const float* src = W + ((size_t)h * D + row) * D + col;
        uint4 v;
        v.x = pk2(src[0], src[1]);
        v.y = pk2(src[2], src[3]);
        v.z = pk2(src[4], src[5]);
        v.w = pk2(src[6], src[7]);
        Wt[((size_t)h * 8 + g) * 64 + l] = v;
    }
}

__global__ __launch_bounds__(256)
void block_linear_mfma(const uint4* __restrict__ Wt,
                       const float* __restrict__ inp,
                       float* __restrict__ out)
{
    const int tid = threadIdx.x;
    const int l   = tid & 63;
    const int wv  = __builtin_amdgcn_readfirstlane(tid >> 6);
    const int h   = blockIdx.y;
    const int l15 = l & 15;
    const int lk8 = (l >> 4) * 8;
    const int lr4 = (l >> 4) * 4;
    const unsigned c0 = (unsigned)blockIdx.x * 64 + wv * 16;   // wave's 16 cols

    const float* __restrict__ Xb = inp + (size_t)h * D * B;
    float*       __restrict__ Ob = out + (size_t)h * D * B;

    // ---- 1) Issue the 16 x loads (HBM, long latency) first.
    unsigned xo[16];
    #pragma unroll
    for (int ks = 0; ks < 2; ++ks)
        #pragma unroll
        for (int r = 0; r < 8; ++r)
            xo[ks * 8 + r] = (unsigned)(ks * 32 + lk8 + r) * B + c0 + l15;

    float xv[16];
    #pragma unroll
    for (int k = 0; k < 16; ++k)
        xv[k] = Xb[xo[k]];

    // ---- 2) W fragments: 8 coalesced uint4 loads from the hot table.
    bf16x8 bfrag[4][2];
    const uint4* wt = Wt + (size_t)h * 8 * 64 + l;
    #pragma unroll
    for (int ni = 0; ni < 4; ++ni)
        #pragma unroll
        for (int ks = 0; ks < 2; ++ks) {
            union { uint4 q; bf16x8 v; } u;
            u.q = wt[(ni * 2 + ks) * 64];
            bfrag[ni][ks] = u.v;
        }

    // ---- 3) Convert x to the A fragments.
    bf16x8 a[2];
    #pragma unroll
    for (int ks = 0; ks < 2; ++ks) {
        union { bf16x8 v; unsigned u[4]; } f;
        f.u[0] = pk2(xv[ks * 8 + 0], xv[ks * 8 + 1]);
        f.u[1] = pk2(xv[ks * 8 + 2], xv[ks * 8 + 3]);
        f.u[2] = pk2(xv[ks * 8 + 4], xv[ks * 8 + 5]);
        f.u[3] = pk2(xv[ks * 8 + 6], xv[ks * 8 + 7]);
        a[ks] = f.v;
    }

    // ---- 4) 8 MFMA + 4 float4 stores.
    #pragma unroll
    for (int ni = 0; ni < 4; ++ni) {
        f32x4 c = {0.f, 0.f, 0.f, 0.f};
        c = __builtin_amdgcn_mfma_f32_16x16x32_bf16(a[0], bfrag[ni][0], c, 0, 0, 0);
        c = __builtin_amdgcn_mfma_f32_16x16x32_bf16(a[1], bfrag[ni][1], c, 0, 0, 0);
        float* op = Ob + (size_t)(16 * ni + l15) * B + c0 + lr4;
        float4 v = make_float4(c[0], c[1], c[2], c[3]);
        *(float4*)op = v;
    }
}

extern "C" void kernel_launch(void* const* d_in, const int* in_sizes, int n_in,
                              void* d_out, int out_size, void* d_ws, size_t ws_size,
                              hipStream_t stream) {
    const float* W   = (const float*)d_in[0];
    const float* inp = (const float*)d_in[1];
    float*       out = (float*)d_out;
    uint4*       Wt  = (uint4*)d_ws;   // 16*8*64*16 B = 128 KB fragment table

    build_wt<<<dim3(H), dim3(256), 0, stream>>>(W, Wt);

    dim3 grid(B / 64, H);   // 512 x 16 = 8192 workgroups; 64 cols per block
    block_linear_mfma<<<grid, dim3(256), 0, stream>>>(Wt, inp, out);
}

// Round 11
// 52.167 us; speedup vs baseline: 1.1266x; 1.1266x over previous
//
#include <hip/hip_runtime.h>
#include <hip/hip_bf16.h>

// BlockLinear: out[h*64+i][b] = sum_j W[h][i][j] * inp[h*64+j][b]
// Round 11: burst-length experiment. r7-r10 (4 schedules, occ 17%->64%) all
// flat at 54-59 us, traffic constant -> limiter is DRAM burst granularity
// (64 B chunks across 64 open rows per wave), not TLP/MLP. This round:
// stores go acc -> LDS tile -> cooperative readback so each store instr
// writes ONE 512 B contiguous row-run (8x longer bursts). Reads unchanged
// (isolate the variable). W via r10's bf16 fragment table (L2-hot).
// Fragment layout (HW-validated r6-r10): lane l holds k = ks*32+8*(l>>4)+r;
// C/D: batch col m = 4*(l>>4)+reg, output row n = l&15.

constexpr int H    = 16;
constexpr int D    = 64;
constexpr int B    = 32768;
constexpr int COLS = 128;   // cols per block (4 waves x 32)
constexpr int LDSW = 132;   // LDS row stride in floats (16B-aligned, bank-spread)

using bf16x8 = __attribute__((ext_vector_type(8))) short;
using f32x4  = __attribute__((ext_vector_type(4))) float;

__device__ inline unsigned pk2(float a, float b) {
    __hip_bfloat162 h2 = __float22bfloat162_rn(make_float2(a, b));
    union { __hip_bfloat162 h; unsigned u; } c;
    c.h = h2;
    return c.u;   // low 16 = a, high 16 = b
}

// Pre-kernel (validated r10): Wt[(h*8 + ni*2 + ks)*64 + l] = bf16 frag chunk
// = W[h][16*ni + (l&15)][ks*32 + (l>>4)*8 + 0..7] packed as 4 u32.
__global__ void build_wt(const float* __restrict__ W, uint4* __restrict__ Wt)
{
    const int h = blockIdx.x;
    const int t = threadIdx.x;
    #pragma unroll
    for (int s = 0; s < 2; ++s) {
        const int c  = t + s * 256;
        const int g  = c >> 6;
        const int l  = c & 63;
        const int ni = g >> 1;
        const int ks = g & 1;
        const int row = 16 * ni + (l & 15);
        const int col = ks * 32 + (l >> 4) * 8;
        const float* src = W + ((size_t)h * D + row) * D + col;
        uint4 v;
        v.x = pk2(src[0], src[1]);
        v.y = pk2(src[2], src[3]);
        v.z = pk2(src[4], src[5]);
        v.w = pk2(src[6], src[7]);
        Wt[((size_t)h * 8 + g) * 64 + l] = v;
    }
}

__global__ __launch_bounds__(256)
void block_linear_mfma(const uint4* __restrict__ Wt,
                       const float* __restrict__ inp,
                       float* __restrict__ out)
{
    __shared__ float cbuf[D * LDSW];   // 64 x 132 fp32 = 33.8 KB

    const int tid = threadIdx.x;
    const int l   = tid & 63;
    const int wv  = __builtin_amdgcn_readfirstlane(tid >> 6);
    const int h   = blockIdx.y;
    const int l15 = l & 15;
    const int lk8 = (l >> 4) * 8;
    const int lr4 = (l >> 4) * 4;

    const unsigned colbase = (unsigned)blockIdx.x * COLS;
    const unsigned wavecol = colbase + wv * 32;

    const float* __restrict__ Xb = inp + (size_t)h * D * B;
    float*       __restrict__ Ob = out + (size_t)h * D * B;

    // ---- 1) Issue the 32 x loads (HBM) first.
    float xv[2][2][8];
    #pragma unroll
    for (int mi = 0; mi < 2; ++mi)
        #pragma unroll
        for (int ks = 0; ks < 2; ++ks)
            #pragma unroll
            for (int r = 0; r < 8; ++r)
                xv[mi][ks][r] =
                    Xb[(size_t)(ks * 32 + lk8 + r) * B + wavecol + 16 * mi + l15];

    // ---- 2) W fragments: 8 coalesced uint4 from the hot table (no convert).
    bf16x8 bfrag[4][2];
    const uint4* wt = Wt + (size_t)h * 8 * 64 + l;
    #pragma unroll
    for (int ni = 0; ni < 4; ++ni)
        #pragma unroll
        for (int ks = 0; ks < 2; ++ks) {
            union { uint4 q; bf16x8 v; } u;
            u.q = wt[(ni * 2 + ks) * 64];
            bfrag[ni][ks] = u.v;
        }

    // ---- 3) Convert x to A fragments.
    bf16x8 a[2][2];
    #pragma unroll
    for (int mi = 0; mi < 2; ++mi)
        #pragma unroll
        for (int ks = 0; ks < 2; ++ks) {
            const float* e = xv[mi][ks];
            union { bf16x8 v; unsigned u[4]; } f;
            f.u[0] = pk2(e[0], e[1]);
            f.u[1] = pk2(e[2], e[3]);
            f.u[2] = pk2(e[4], e[5]);
            f.u[3] = pk2(e[6], e[7]);
            a[mi][ks] = f.v;
        }

    // ---- 4) MFMA; acc -> LDS tile (row = out row, col = block-local col).
    #pragma unroll
    for (int mi = 0; mi < 2; ++mi)
        #pragma unroll
        for (int ni = 0; ni < 4; ++ni) {
            f32x4 c = {0.f, 0.f, 0.f, 0.f};
            c = __builtin_amdgcn_mfma_f32_16x16x32_bf16(a[mi][0], bfrag[ni][0], c, 0, 0, 0);
            c = __builtin_amdgcn_mfma_f32_16x16x32_bf16(a[mi][1], bfrag[ni][1], c, 0, 0, 0);
            const int row  = 16 * ni + l15;
            const int colt = wv * 32 + 16 * mi + lr4;
            float4 v = make_float4(c[0], c[1], c[2], c[3]);
            *(float4*)&cbuf[row * LDSW + colt] = v;
        }

    __syncthreads();

    // ---- 5) Cooperative stores: each instr = ONE 512 B contiguous row-run.
    #pragma unroll
    for (int rr = 0; rr < D / 4; ++rr) {
        const int row = wv * 16 + rr;
        float2 v = *(const float2*)&cbuf[row * LDSW + 2 * l];
        *(float2*)(Ob + (size_t)row * B + colbase + 2 * l) = v;
    }
}

extern "C" void kernel_launch(void* const* d_in, const int* in_sizes, int n_in,
                              void* d_out, int out_size, void* d_ws, size_t ws_size,
                              hipStream_t stream) {
    const float* W   = (const float*)d_in[0];
    const float* inp = (const float*)d_in[1];
    float*       out = (float*)d_out;
    uint4*       Wt  = (uint4*)d_ws;   // 128 KB fragment table

    build_wt<<<dim3(H), dim3(256), 0, stream>>>(W, Wt);

    dim3 grid(B / COLS, H);   // 256 x 16 = 4096 workgroups
    block_linear_mfma<<<grid, dim3(256), 0, stream>>>(Wt, inp, out);
}

// Round 13
// 50.692 us; speedup vs baseline: 1.1594x; 1.0291x over previous
//
#include <hip/hip_runtime.h>
#include <hip/hip_bf16.h>

// BlockLinear: out[h*64+i][b] = sum_j W[h][i][j] * inp[h*64+j][b]
// Round 13: r11 + non-temporal cooperative stores (r12 fixed: builtin needs a
// NATIVE vector type, not HIP's float2 class -> use ext_vector_type(2)).
// Rationale: inp(128MB)+out(128MB) = 256MB = L3 size -> out's L3 allocation
// evicts half of inp every replay (steady FETCH pinned ~69 MB). nt-stores on
// fully-covered aligned 512 B runs should skip L3 allocation without the
// write amplification r8 saw on scattered 64 B chunks.
// Fragment layout (HW-validated r6-r11): lane l holds k = ks*32+8*(l>>4)+r;
// C/D: batch col m = 4*(l>>4)+reg, output row n = l&15.

constexpr int H    = 16;
constexpr int D    = 64;
constexpr int B    = 32768;
constexpr int COLS = 128;   // cols per block (4 waves x 32)
constexpr int LDSW = 132;   // LDS row stride in floats (16B-aligned, bank-spread)

using bf16x8 = __attribute__((ext_vector_type(8))) short;
using f32x4  = __attribute__((ext_vector_type(4))) float;
using f32x2  = __attribute__((ext_vector_type(2))) float;   // native vec for nt-store

__device__ inline unsigned pk2(float a, float b) {
    __hip_bfloat162 h2 = __float22bfloat162_rn(make_float2(a, b));
    union { __hip_bfloat162 h; unsigned u; } c;
    c.h = h2;
    return c.u;   // low 16 = a, high 16 = b
}

// Pre-kernel (validated r10/r11): Wt[(h*8 + ni*2 + ks)*64 + l] = bf16 frag
// chunk = W[h][16*ni + (l&15)][ks*32 + (l>>4)*8 + 0..7] packed as 4 u32.
__global__ void build_wt(const float* __restrict__ W, uint4* __restrict__ Wt)
{
    const int h = blockIdx.x;
    const int t = threadIdx.x;
    #pragma unroll
    for (int s = 0; s < 2; ++s) {
        const int c  = t + s * 256;
        const int g  = c >> 6;
        const int l  = c & 63;
        const int ni = g >> 1;
        const int ks = g & 1;
        const int row = 16 * ni + (l & 15);
        const int col = ks * 32 + (l >> 4) * 8;
        const float* src = W + ((size_t)h * D + row) * D + col;
        uint4 v;
        v.x = pk2(src[0], src[1]);
        v.y = pk2(src[2], src[3]);
        v.z = pk2(src[4], src[5]);
        v.w = pk2(src[6], src[7]);
        Wt[((size_t)h * 8 + g) * 64 + l] = v;
    }
}

__global__ __launch_bounds__(256)
void block_linear_mfma(const uint4* __restrict__ Wt,
                       const float* __restrict__ inp,
                       float* __restrict__ out)
{
    __shared__ float cbuf[D * LDSW];   // 64 x 132 fp32 = 33.8 KB

    const int tid = threadIdx.x;
    const int l   = tid & 63;
    const int wv  = __builtin_amdgcn_readfirstlane(tid >> 6);
    const int h   = blockIdx.y;
    const int l15 = l & 15;
    const int lk8 = (l >> 4) * 8;
    const int lr4 = (l >> 4) * 4;

    const unsigned colbase = (unsigned)blockIdx.x * COLS;
    const unsigned wavecol = colbase + wv * 32;

    const float* __restrict__ Xb = inp + (size_t)h * D * B;
    float*       __restrict__ Ob = out + (size_t)h * D * B;

    // ---- 1) Issue the 32 x loads (HBM) first.
    float xv[2][2][8];
    #pragma unroll
    for (int mi = 0; mi < 2; ++mi)
        #pragma unroll
        for (int ks = 0; ks < 2; ++ks)
            #pragma unroll
            for (int r = 0; r < 8; ++r)
                xv[mi][ks][r] =
                    Xb[(size_t)(ks * 32 + lk8 + r) * B + wavecol + 16 * mi + l15];

    // ---- 2) W fragments: 8 coalesced uint4 from the hot table (no convert).
    bf16x8 bfrag[4][2];
    const uint4* wt = Wt + (size_t)h * 8 * 64 + l;
    #pragma unroll
    for (int ni = 0; ni < 4; ++ni)
        #pragma unroll
        for (int ks = 0; ks < 2; ++ks) {
            union { uint4 q; bf16x8 v; } u;
            u.q = wt[(ni * 2 + ks) * 64];
            bfrag[ni][ks] = u.v;
        }

    // ---- 3) Convert x to A fragments.
    bf16x8 a[2][2];
    #pragma unroll
    for (int mi = 0; mi < 2; ++mi)
        #pragma unroll
        for (int ks = 0; ks < 2; ++ks) {
            const float* e = xv[mi][ks];
            union { bf16x8 v; unsigned u[4]; } f;
            f.u[0] = pk2(e[0], e[1]);
            f.u[1] = pk2(e[2], e[3]);
            f.u[2] = pk2(e[4], e[5]);
            f.u[3] = pk2(e[6], e[7]);
            a[mi][ks] = f.v;
        }

    // ---- 4) MFMA; acc -> LDS tile (row = out row, col = block-local col).
    #pragma unroll
    for (int mi = 0; mi < 2; ++mi)
        #pragma unroll
        for (int ni = 0; ni < 4; ++ni) {
            f32x4 c = {0.f, 0.f, 0.f, 0.f};
            c = __builtin_amdgcn_mfma_f32_16x16x32_bf16(a[mi][0], bfrag[ni][0], c, 0, 0, 0);
            c = __builtin_amdgcn_mfma_f32_16x16x32_bf16(a[mi][1], bfrag[ni][1], c, 0, 0, 0);
            const int row  = 16 * ni + l15;
            const int colt = wv * 32 + 16 * mi + lr4;
            float4 v = make_float4(c[0], c[1], c[2], c[3]);
            *(float4*)&cbuf[row * LDSW + colt] = v;
        }

    __syncthreads();

    // ---- 5) Cooperative NON-TEMPORAL stores: each instr writes one aligned,
    // fully-covered 512 B row-run -> full-line writes, no L3 allocation.
    #pragma unroll
    for (int rr = 0; rr < D / 4; ++rr) {
        const int row = wv * 16 + rr;
        f32x2 v = *(const f32x2*)&cbuf[row * LDSW + 2 * l];
        __builtin_nontemporal_store(
            v, (f32x2*)(Ob + (size_t)row * B + colbase + 2 * l));
    }
}

extern "C" void kernel_launch(void* const* d_in, const int* in_sizes, int n_in,
                              void* d_out, int out_size, void* d_ws, size_t ws_size,
                              hipStream_t stream) {
    const float* W   = (const float*)d_in[0];
    const float* inp = (const float*)d_in[1];
    float*       out = (float*)d_out;
    uint4*       Wt  = (uint4*)d_ws;   // 128 KB fragment table

    build_wt<<<dim3(H), dim3(256), 0, stream>>>(W, Wt);

    dim3 grid(B / COLS, H);   // 256 x 16 = 4096 workgroups
    block_linear_mfma<<<grid, dim3(256), 0, stream>>>(Wt, inp, out);
}

// Round 14
// 49.467 us; speedup vs baseline: 1.1881x; 1.0248x over previous
//
#include <hip/hip_runtime.h>
#include <hip/hip_bf16.h>

// BlockLinear: out[h*64+i][b] = sum_j W[h][i][j] * inp[h*64+j][b]
// Round 14: copy-style READS. r7-r13 established: schedules/occupancy don't
// move dur (54->50.7 us); only burst-widening did (+4% writes r11, +3% nt
// r13). Reads are the last 64 B-granule stream: fragment layout forces
// k(=row, 128 KB stride) per-lane -> 4x64 B segments per load instr. Fix:
// cooperative float4 loads (1 KB contiguous per wave instr) -> LDS row-major
// (stride 133: frag ds_read_b32 banks = 8g+l15+5r -> 2 lanes/bank = free)
// -> fragments from LDS. C staging + coop f32x4 nt-stores as r13. One 34 KB
// LDS buffer reused x->C across barriers.
// Fragment layout (HW-validated r6-r13): lane l holds k = ks*32+8*(l>>4)+r;
// C/D: batch col m = 4*(l>>4)+reg, output row n = l&15.

constexpr int H    = 16;
constexpr int D    = 64;
constexpr int B    = 32768;
constexpr int COLS = 128;   // cols per block (4 waves x 32)
constexpr int XS   = 133;   // x LDS row stride (frag reads 2-way/free)
constexpr int CS   = 132;   // C LDS row stride (r11/r13: 0 conflicts)

using bf16x8 = __attribute__((ext_vector_type(8))) short;
using f32x4  = __attribute__((ext_vector_type(4))) float;

__device__ inline unsigned pk2(float a, float b) {
    __hip_bfloat162 h2 = __float22bfloat162_rn(make_float2(a, b));
    union { __hip_bfloat162 h; unsigned u; } c;
    c.h = h2;
    return c.u;   // low 16 = a, high 16 = b
}

// Pre-kernel (validated r10-r13): Wt[(h*8 + ni*2 + ks)*64 + l] = bf16 frag
// chunk = W[h][16*ni + (l&15)][ks*32 + (l>>4)*8 + 0..7] packed as 4 u32.
__global__ void build_wt(const float* __restrict__ W, uint4* __restrict__ Wt)
{
    const int h = blockIdx.x;
    const int t = threadIdx.x;
    #pragma unroll
    for (int s = 0; s < 2; ++s) {
        const int c  = t + s * 256;
        const int g  = c >> 6;
        const int l  = c & 63;
        const int ni = g >> 1;
        const int ks = g & 1;
        const int row = 16 * ni + (l & 15);
        const int col = ks * 32 + (l >> 4) * 8;
        const float* src = W + ((size_t)h * D + row) * D + col;
        uint4 v;
        v.x = pk2(src[0], src[1]);
        v.y = pk2(src[2], src[3]);
        v.z = pk2(src[4], src[5]);
        v.w = pk2(src[6], src[7]);
        Wt[((size_t)h * 8 + g) * 64 + l] = v;
    }
}

__global__ __launch_bounds__(256)
void block_linear_mfma(const uint4* __restrict__ Wt,
                       const float* __restrict__ inp,
                       float* __restrict__ out)
{
    __shared__ float lds[D * XS];   // 64*133*4 = 34 KB; reused x -> C

    const int tid = threadIdx.x;
    const int l   = tid & 63;
    const int wv  = __builtin_amdgcn_readfirstlane(tid >> 6);
    const int h   = blockIdx.y;
    const int l15 = l & 15;
    const int lk8 = (l >> 4) * 8;
    const int lr4 = (l >> 4) * 4;

    const unsigned colbase = (unsigned)blockIdx.x * COLS;

    const float* __restrict__ Xb = inp + (size_t)h * D * B;
    float*       __restrict__ Ob = out + (size_t)h * D * B;

    // ---- W fragments: 8 coalesced uint4 from the hot table.
    bf16x8 bfrag[4][2];
    const uint4* wt = Wt + (size_t)h * 8 * 64 + l;
    #pragma unroll
    for (int ni = 0; ni < 4; ++ni)
        #pragma unroll
        for (int ks = 0; ks < 2; ++ks) {
            union { uint4 q; bf16x8 v; } u;
            u.q = wt[(ni * 2 + ks) * 64];
            bfrag[ni][ks] = u.v;
        }

    // ---- Phase 1: copy-style reads. Each wave instr = 1 KB contiguous
    // (2 rows x 512 B runs). 8 float4/thread; all 8 in flight together.
    float4 xp[8];
    #pragma unroll
    for (int p = 0; p < 8; ++p) {
        const int idx = p * 256 + tid;
        const int row = idx >> 5;
        const int c4  = (idx & 31) << 2;
        xp[p] = *(const float4*)(Xb + (size_t)row * B + colbase + c4);
    }
    #pragma unroll
    for (int p = 0; p < 8; ++p) {
        const int idx = p * 256 + tid;
        const int row = idx >> 5;
        const int c4  = (idx & 31) << 2;
        lds[row * XS + c4 + 0] = xp[p].x;
        lds[row * XS + c4 + 1] = xp[p].y;
        lds[row * XS + c4 + 2] = xp[p].z;
        lds[row * XS + c4 + 3] = xp[p].w;
    }
    __syncthreads();

    // ---- Phase 2: A fragments from LDS (32 ds_read_b32/wave, 2-way = free).
    bf16x8 a[2][2];
    #pragma unroll
    for (int mi = 0; mi < 2; ++mi)
        #pragma unroll
        for (int ks = 0; ks < 2; ++ks) {
            const int c = wv * 32 + 16 * mi + l15;
            float e[8];
            #pragma unroll
            for (int r = 0; r < 8; ++r)
                e[r] = lds[(ks * 32 + lk8 + r) * XS + c];
            union { bf16x8 v; unsigned u[4]; } f;
            f.u[0] = pk2(e[0], e[1]);
            f.u[1] = pk2(e[2], e[3]);
            f.u[2] = pk2(e[4], e[5]);
            f.u[3] = pk2(e[6], e[7]);
            a[mi][ks] = f.v;
        }
    __syncthreads();   // all x reads done before C overwrites the buffer

    // ---- Phase 3: MFMA; stage C into the same LDS (stride 132).
    #pragma unroll
    for (int mi = 0; mi < 2; ++mi)
        #pragma unroll
        for (int ni = 0; ni < 4; ++ni) {
            f32x4 c = {0.f, 0.f, 0.f, 0.f};
            c = __builtin_amdgcn_mfma_f32_16x16x32_bf16(a[mi][0], bfrag[ni][0], c, 0, 0, 0);
            c = __builtin_amdgcn_mfma_f32_16x16x32_bf16(a[mi][1], bfrag[ni][1], c, 0, 0, 0);
            const int row  = 16 * ni + l15;
            const int colt = wv * 32 + 16 * mi + lr4;
            *(f32x4*)&lds[row * CS + colt] = c;
        }
    __syncthreads();

    // ---- Phase 4: cooperative nt-stores, f32x4 (2 rows x 512 B per instr).
    #pragma unroll
    for (int p = 0; p < 8; ++p) {
        const int idx = p * 256 + tid;
        const int row = idx >> 5;
        const int c4  = (idx & 31) << 2;
        f32x4 v = *(const f32x4*)&lds[row * CS + c4];
        __builtin_nontemporal_store(
            v, (f32x4*)(Ob + (size_t)row * B + colbase + c4));
    }
}

extern "C" void kernel_launch(void* const* d_in, const int* in_sizes, int n_in,
                              void* d_out, int out_size, void* d_ws, size_t ws_size,
                              hipStream_t stream) {
    const float* W   = (const float*)d_in[0];
    const float* inp = (const float*)d_in[1];
    float*       out = (float*)d_out;
    uint4*       Wt  = (uint4*)d_ws;   // 128 KB fragment table

    build_wt<<<dim3(H), dim3(256), 0, stream>>>(W, Wt);

    dim3 grid(B / COLS, H);   // 256 x 16 = 4096 workgroups
    block_linear_mfma<<<grid, dim3(256), 0, stream>>>(Wt, inp, out);
}